// Round 8
// baseline (253.790 us; speedup 1.0000x reference)
//
#include <hip/hip_runtime.h>
#include <hip/hip_fp16.h>
#include <cstddef>

// AffinityPropagate: per-pixel normalized 3x3 stencil, 24 steps.
// R13: FEWER, LONGER BLOCKS. Tile 40w x 80h, 768 blocks (was 1536).
// Evidence: every intra-loop lever (barriers R7, LDS width R8/R11, VALU R9,
// LDS issue-count R12) moved wall only +/-10%; Occupancy pinned at 38-40%
// despite resources allowing 32 waves/CU; it rose to 66% only when blocks
// were long-lived (R10). Model: short blocks (~20us) + 1536-block ramp =
// dispatch is half fill/drain at ~1.5 resident blocks/CU. Longer blocks
// raise steady-state fraction AND cut redundancy (px-steps/output 26.4->
// 23.4, staging/output 2.72->2.19, aff reads -19%).
// Thread = 1 col x 13 rows; wave = 64 contiguous cols -> all LDS traffic
// b32 lane-stride-1 (the ONLY conflict-free pattern measured: 0.39M vs
// 5.8M/23.4M cyc for float2/float4). Rolling 3x3 register window (R0/R5
// pattern, compiler software-pipelines it) keeps VGPR ~80-95 (packed half2
// weights = 65 regs; v_fma_mix consumes halves directly, proven R9).
//
// Tap order: w0=NW w1=N w2=NE w3=W [center] w4=E w5=SW w6=S w7=SE
//
// Ring/frontier: staged 106 rows x 66 cols (halo 13), weight region rows
// 0..103 <-> staged rows 1..104, cols staged 1..64. Valid staged ring after
// step s: rows [s,105-s], cols [s,65-s]. Wave w writes staged rows
// 13w+1..13w+13; live while (13w+13 >= s+1) && (13w+1 <= 104-s). After 12
// steps rows 12..93 / cols 12..53 valid; output tile = rows 13..92, cols
// 13..52. Out-of-image px have all-zero weights -> stay exactly 0 = zero
// padding. fB zero-filled -> all garbage finite and provably outside ring.

#define HIMG 480
#define WIMG 640
#define HW   (HIMG * WIMG)
#define BN   8

#define TILEW  40
#define TILEH  80
#define NROW   13                // rows per thread (8 waves x 13 = 104)
#define TSTEPS 12
#define IH     13                // staged halo
#define WHL    12                // weight halo
#define SROWS  106               // staged rows
#define SCOLS  66                // staged cols
#define PITCH  68                // LDS row pitch (floats)
#define NT     512

#define WS_FRAME_B  ((size_t)BN * HW * 4)            // 9,830,400
#define WS_WA_B     ((size_t)BN * HW * 16)           // 39,321,600
#define WS_WC_B     ((size_t)BN * HW * 4)            // 9,830,400
#define WS_NEED     (WS_FRAME_B + WS_WA_B + WS_WC_B) // 58,982,400

// MODE: 0 = normalize in-kernel + store interior weights to wA/wC
//       1 = load packed weights from wA/wC
//       2 = normalize in-kernel, no store (fallback when ws too small)
template <int MODE>
__global__ __launch_bounds__(NT, 2) void affprop12(
    const float* __restrict__ aff,
    __half2* __restrict__ wA,
    float* __restrict__ wC,
    const float* __restrict__ src,
    float* __restrict__ dst)
{
    __shared__ float fA[SROWS * PITCH];
    __shared__ float fB[SROWS * PITCH];

    const int tid = threadIdx.x;
    const int ox  = blockIdx.x * TILEW;
    const int oy  = blockIdx.y * TILEH;
    const int b   = blockIdx.z;

    const float* __restrict__ sb = src + (size_t)b * HW;
    float*       __restrict__ db = dst + (size_t)b * HW;

    // ---- stage input region [oy-13,oy+93) x [ox-13,ox+53), 0 outside image
    for (int i = tid; i < SROWS * SCOLS; i += NT) {
        int r  = i / SCOLS;
        int c  = i - r * SCOLS;
        int gy = oy - IH + r;
        int gx = ox - IH + c;
        float v = 0.f;
        if ((unsigned)gy < (unsigned)HIMG && (unsigned)gx < (unsigned)WIMG)
            v = sb[gy * WIMG + gx];
        fA[r * PITCH + c] = v;
    }
    // ---- zero-fill buffer B (deterministic stale rings)
    for (int i = tid; i < SROWS * PITCH / 4; i += NT)
        *(float4*)&fB[4 * i] = make_float4(0.f, 0.f, 0.f, 0.f);

    // ---- per-thread: weight column c, wave w owns weight rows 13w..13w+12
    const int c  = tid & 63;          // weight col 0..63
    const int w  = tid >> 6;          // wave id 0..7
    const int sc = c + 1;             // staged col of this thread's outputs

    __half2 wv[NROW][4];  // [row i][tap pair (01)(23)(45)(67)] packed
    float   wcc[NROW];    // center weights (f32)

    #pragma unroll
    for (int i = 0; i < NROW; ++i) {
        const int gy = oy - WHL + NROW * w + i;
        const int gx = ox - WHL + c;
        const bool in = (unsigned)gy < (unsigned)HIMG && (unsigned)gx < (unsigned)WIMG;
        const size_t idx = (size_t)b * HW + (size_t)gy * WIMG + gx;

        if (MODE == 1) {
            if (in) {
                union { float4 f4; __half2 h[4]; } u;
                u.f4 = *(const float4*)(wA + 4 * idx);
                wv[i][0] = u.h[0]; wv[i][1] = u.h[1];
                wv[i][2] = u.h[2]; wv[i][3] = u.h[3];
                wcc[i] = wC[idx];
            } else {
                __half2 z = __floats2half2_rn(0.f, 0.f);
                wv[i][0] = z; wv[i][1] = z; wv[i][2] = z; wv[i][3] = z;
                wcc[i] = 0.f;
            }
        } else {
            float wt[8];
            float s = 0.f;
            if (in) {
                const float* ap = aff + (size_t)b * 8 * HW + (size_t)gy * WIMG + gx;
                #pragma unroll
                for (int k = 0; k < 8; ++k) { wt[k] = ap[(size_t)k * HW]; s += fabsf(wt[k]); }
            } else {
                #pragma unroll
                for (int k = 0; k < 8; ++k) wt[k] = 0.f;
                s = 1.f;
            }
            float rr  = in ? 1.0f / s : 0.f;
            float acc = 0.f;
            #pragma unroll
            for (int k = 0; k < 8; ++k) { wt[k] *= rr; acc += wt[k]; }

            union { float4 f4; __half2 h[4]; } u;
            u.h[0] = __floats2half2_rn(wt[0], wt[1]);
            u.h[1] = __floats2half2_rn(wt[2], wt[3]);
            u.h[2] = __floats2half2_rn(wt[4], wt[5]);
            u.h[3] = __floats2half2_rn(wt[6], wt[7]);
            wv[i][0] = u.h[0]; wv[i][1] = u.h[1];
            wv[i][2] = u.h[2]; wv[i][3] = u.h[3];
            wcc[i] = in ? 1.0f - acc : 0.f;

            if (MODE == 0) {
                // store interior weights for launch 2 (each image px interior
                // to exactly one block)
                if ((unsigned)(gy - oy) < (unsigned)TILEH &&
                    (unsigned)(gx - ox) < (unsigned)TILEW) {
                    *(float4*)(wA + 4 * idx) = u.f4;
                    wC[idx] = wcc[i];
                }
            }
        }
    }
    __syncthreads();

    // ---- 12 fused steps; rolling 3x3 window, stride-1 b32 LDS only
    const float* fin = fA;
    float*       fo  = fB;

    #pragma unroll 1
    for (int s = 0; s < TSTEPS; ++s) {
        // wave-uniform liveness: wave w writes staged rows 13w+1..13w+13;
        // rows needed after step s: [s+1, 104-s]
        const bool live = (NROW * w + NROW >= s + 1) && (NROW * w + 1 <= 104 - s);
        if (live) {
            const float* rp = fin + (NROW * w) * PITCH + c;  // staged cols sc-1..sc+1
            float a0 = rp[0], a1 = rp[1], a2 = rp[2];
            rp += PITCH;
            float b0 = rp[0], b1 = rp[1], b2 = rp[2];
            float* wp = fo + (NROW * w + 1) * PITCH + sc;

            #pragma unroll
            for (int i = 0; i < NROW; ++i) {
                rp += PITCH;
                float c0 = rp[0], c1 = rp[1], c2 = rp[2];

                float o = wcc[i] * b1
                    + __low2float (wv[i][0]) * a0    // NW
                    + __high2float(wv[i][0]) * a1    // N
                    + __low2float (wv[i][1]) * a2    // NE
                    + __high2float(wv[i][1]) * b0    // W
                    + __low2float (wv[i][2]) * b2    // E
                    + __high2float(wv[i][2]) * c0    // SW
                    + __low2float (wv[i][3]) * c1    // S
                    + __high2float(wv[i][3]) * c2;   // SE

                *wp = o;
                wp += PITCH;
                a0 = b0; a1 = b1; a2 = b2;
                b0 = c0; b1 = c1; b2 = c2;
            }
        }
        __syncthreads();
        const float* t = fin; fin = fo; fo = (float*)t;
    }

    // ---- store 80x40 tile (fin == fA after 12 steps)
    for (int i = tid; i < TILEH * (TILEW / 4); i += NT) {
        int r  = i / (TILEW / 4);
        int c4 = (i - r * (TILEW / 4)) * 4;
        const float* p = fin + (IH + r) * PITCH + IH + c4;
        float4 v = make_float4(p[0], p[1], p[2], p[3]);
        *(float4*)&db[(size_t)(oy + r) * WIMG + ox + c4] = v;
    }
}

extern "C" void kernel_launch(void* const* d_in, const int* in_sizes, int n_in,
                              void* d_out, int out_size, void* d_ws, size_t ws_size,
                              hipStream_t stream)
{
    const float* aff  = (const float*)d_in[0];
    const float* feat = (const float*)d_in[1];
    float* out = (float*)d_out;

    char* ws = (char*)d_ws;
    float*   wsFrame = (float*)ws;
    __half2* wA      = (__half2*)(ws + WS_FRAME_B);
    float*   wC      = (float*)(ws + WS_FRAME_B + WS_WA_B);

    dim3 blk(NT, 1, 1);
    dim3 grd(WIMG / TILEW, HIMG / TILEH, BN);   // 16 x 6 x 8 = 768 blocks

    if (ws_size >= WS_NEED) {
        affprop12<0><<<grd, blk, 0, stream>>>(aff, wA, wC, feat, wsFrame);
        affprop12<1><<<grd, blk, 0, stream>>>(aff, wA, wC, wsFrame, out);
    } else {
        affprop12<2><<<grd, blk, 0, stream>>>(aff, nullptr, nullptr, feat, wsFrame);
        affprop12<2><<<grd, blk, 0, stream>>>(aff, nullptr, nullptr, wsFrame, out);
    }
}

// Round 9
// 231.130 us; speedup vs baseline: 1.0980x; 1.0980x over previous
//
#include <hip/hip_runtime.h>
#include <hip/hip_fp16.h>
#include <cstddef>
#include <cstdint>

// AffinityPropagate: per-pixel normalized 3x3 stencil, 24 steps.
// R14: R9 skeleton (tile 40x40, 1536 blocks, 1col x 8rows/thread, b32
// stride-1 LDS = only conflict-free pattern measured) with the DS-pipe
// instruction count HALVED by forced pairing: inline-asm ds_read2_b32 /
// ds_write2_b32. Same byte addresses, same banks, zero added VALU.
// Per wave-step: 30 reads + 8 writes (38 DS insts) -> 15 read2 + 4 write2
// (19 DS insts). Model: DS pipe was ~132K of 190K wall cy/CU (issue-bound
// at 5.8cy/inst, 44 B/cy of 128 peak); this cuts DS issue ~45%.
// Why forced: R12 showed the compiler does NOT auto-pair these (VALU rose
// instead); read2's 8-bit dword offsets (<=255) handled with 3 read bases
// (rows 0/4/8) + 2 write bases (rows 0/4) per buffer, precomputed.
// Rule 18: after the 15 read2s -> s_waitcnt lgkmcnt(0) + sched_barrier(0).
// R13 lesson kept: >=1536 blocks, ~36KB LDS (4 blocks/CU by LDS).
//
// Tap order: w0=NW w1=N w2=NE w3=W [center] w4=E w5=SW w6=S w7=SE
//
// Ring/frontier: staged halo 13 (66x66), weight halo 12 (64x64 = staged
// rows/cols 1..64, rewritten every step). Valid staged ring after step s:
// [s,65-s]; after 12 steps rows/cols 12..53 valid; output tile is 13..52.
// Out-of-image px have all-zero weights -> stay exactly 0 = zero padding.
// fB zero-filled -> all garbage finite and never read by in-ring outputs.

#define HIMG 480
#define WIMG 640
#define HW   (HIMG * WIMG)
#define BN   8

#define TILE   40
#define TSTEPS 12
#define IH     13                // staged halo
#define WHL    12                // weight halo
#define SW     66                // staged rows/cols
#define PITCH  68                // LDS row pitch (floats)
#define NT     512

#define WS_FRAME_B  ((size_t)BN * HW * 4)            // 9,830,400
#define WS_WA_B     ((size_t)BN * HW * 16)           // 39,321,600
#define WS_WC_B     ((size_t)BN * HW * 4)            // 9,830,400
#define WS_NEED     (WS_FRAME_B + WS_WA_B + WS_WC_B) // 58,982,400

typedef float f32x2 __attribute__((ext_vector_type(2)));

// ds_read2_b32: dst.lo = LDS[a+4*O0], dst.hi = LDS[a+4*O1]; O* dword lits <=255
#define DSR2(d, a, O0, O1)                                                  \
    asm volatile("ds_read2_b32 %0, %1 offset0:" #O0 " offset1:" #O1         \
                 : "=v"(d) : "v"(a))
#define DSW2(a, d0, d1, O0, O1)                                             \
    asm volatile("ds_write2_b32 %0, %1, %2 offset0:" #O0 " offset1:" #O1    \
                 :: "v"(a), "v"(d0), "v"(d1) : "memory")

// One stencil step for one wave-slab: read 10x3 window (15 read2), 8 FMA
// rows, write 8 outputs (4 write2). b0 = LDS byte addr of (row 8g, col c)
// in source buffer; w0 = LDS byte addr of (row 8g+1, col sc) in dest.
__device__ __forceinline__ void step_phase(
    unsigned b0, unsigned w0,
    const __half2 (&wv)[8][4], const float (&wcc)[8])
{
    const unsigned b1 = b0 + 4 * PITCH * 4;   // row 8g+4
    const unsigned b2 = b0 + 8 * PITCH * 4;   // row 8g+8
    f32x2 q0, q1, q2, q3, q4, q5, q6, q7, q8, q9, qa, qb, qc, qd, qe;
    // sides: cols c (=sc-1) and c+2 (=sc+1), rows 0..9
    DSR2(q0, b0, 0,   2);
    DSR2(q1, b0, 68,  70);
    DSR2(q2, b0, 136, 138);
    DSR2(q3, b0, 204, 206);
    DSR2(q4, b1, 0,   2);
    DSR2(q5, b1, 68,  70);
    DSR2(q6, b1, 136, 138);
    DSR2(q7, b1, 204, 206);
    DSR2(q8, b2, 0,   2);
    DSR2(q9, b2, 68,  70);
    // centers: col c+1 (=sc), row pairs (0,1)(2,3)(4,5)(6,7)(8,9)
    DSR2(qa, b0, 1,   69);
    DSR2(qb, b0, 137, 205);
    DSR2(qc, b1, 1,   69);
    DSR2(qd, b1, 137, 205);
    DSR2(qe, b2, 1,   69);
    asm volatile("s_waitcnt lgkmcnt(0)" ::: "memory");
    __builtin_amdgcn_sched_barrier(0);

    float t0[10], t1[10], t2[10];
    t0[0] = q0.x; t2[0] = q0.y;  t0[1] = q1.x; t2[1] = q1.y;
    t0[2] = q2.x; t2[2] = q2.y;  t0[3] = q3.x; t2[3] = q3.y;
    t0[4] = q4.x; t2[4] = q4.y;  t0[5] = q5.x; t2[5] = q5.y;
    t0[6] = q6.x; t2[6] = q6.y;  t0[7] = q7.x; t2[7] = q7.y;
    t0[8] = q8.x; t2[8] = q8.y;  t0[9] = q9.x; t2[9] = q9.y;
    t1[0] = qa.x; t1[1] = qa.y;  t1[2] = qb.x; t1[3] = qb.y;
    t1[4] = qc.x; t1[5] = qc.y;  t1[6] = qd.x; t1[7] = qd.y;
    t1[8] = qe.x; t1[9] = qe.y;

    float o[8];
    #pragma unroll
    for (int i = 0; i < 8; ++i) {
        o[i] = wcc[i] * t1[i + 1]
            + __low2float (wv[i][0]) * t0[i]        // NW
            + __high2float(wv[i][0]) * t1[i]        // N
            + __low2float (wv[i][1]) * t2[i]        // NE
            + __high2float(wv[i][1]) * t0[i + 1]    // W
            + __low2float (wv[i][2]) * t2[i + 1]    // E
            + __high2float(wv[i][2]) * t0[i + 2]    // SW
            + __low2float (wv[i][3]) * t1[i + 2]    // S
            + __high2float(wv[i][3]) * t2[i + 2];   // SE
    }
    const unsigned w1 = w0 + 4 * PITCH * 4;   // row 8g+5
    DSW2(w0, o[0], o[1], 0,   68);
    DSW2(w0, o[2], o[3], 136, 204);
    DSW2(w1, o[4], o[5], 0,   68);
    DSW2(w1, o[6], o[7], 136, 204);
}

// MODE: 0 = normalize in-kernel + store interior weights to wA/wC
//       1 = load packed weights from wA/wC
//       2 = normalize in-kernel, no store (fallback when ws too small)
template <int MODE>
__global__ __launch_bounds__(NT, 3) void affprop12(
    const float* __restrict__ aff,
    __half2* __restrict__ wA,
    float* __restrict__ wC,
    const float* __restrict__ src,
    float* __restrict__ dst)
{
    __shared__ float fA[SW * PITCH];
    __shared__ float fB[SW * PITCH];

    const int tid = threadIdx.x;
    const int ox  = blockIdx.x * TILE;
    const int oy  = blockIdx.y * TILE;
    const int b   = blockIdx.z;

    const float* __restrict__ sb = src + (size_t)b * HW;
    float*       __restrict__ db = dst + (size_t)b * HW;

    // ---- stage input region [oy-13, oy+53) x [ox-13, ox+53), 0 outside image
    for (int i = tid; i < SW * SW; i += NT) {
        int r  = i / SW;
        int c  = i - r * SW;
        int gy = oy - IH + r;
        int gx = ox - IH + c;
        float v = 0.f;
        if ((unsigned)gy < (unsigned)HIMG && (unsigned)gx < (unsigned)WIMG)
            v = sb[gy * WIMG + gx];
        fA[r * PITCH + c] = v;
    }
    // ---- zero-fill buffer B (deterministic stale rings)
    for (int i = tid; i < SW * PITCH / 4; i += NT)
        *(float4*)&fB[4 * i] = make_float4(0.f, 0.f, 0.f, 0.f);

    // ---- per-thread: weight column c, row group g (8 rows)
    const int c  = tid & 63;          // weight col 0..63
    const int g  = tid >> 6;          // row group 0..7
    const int sc = c + 1;             // staged col of this thread's outputs

    __half2 wv[8][4];   // [row i][tap pair (01)(23)(45)(67)]
    float   wcc[8];     // center weights (f32)

    #pragma unroll
    for (int i = 0; i < 8; ++i) {
        const int gy = oy - WHL + 8 * g + i;
        const int gx = ox - WHL + c;
        const bool in = (unsigned)gy < (unsigned)HIMG && (unsigned)gx < (unsigned)WIMG;
        const size_t idx = (size_t)b * HW + (size_t)gy * WIMG + gx;

        if (MODE == 1) {
            if (in) {
                union { float4 f4; __half2 h[4]; } u;
                u.f4 = *(const float4*)(wA + 4 * idx);
                wv[i][0] = u.h[0]; wv[i][1] = u.h[1];
                wv[i][2] = u.h[2]; wv[i][3] = u.h[3];
                wcc[i] = wC[idx];
            } else {
                __half2 z = __floats2half2_rn(0.f, 0.f);
                wv[i][0] = z; wv[i][1] = z; wv[i][2] = z; wv[i][3] = z;
                wcc[i] = 0.f;
            }
        } else {
            float w[8];
            float s = 0.f;
            if (in) {
                const float* ap = aff + (size_t)b * 8 * HW + (size_t)gy * WIMG + gx;
                #pragma unroll
                for (int k = 0; k < 8; ++k) { w[k] = ap[(size_t)k * HW]; s += fabsf(w[k]); }
            } else {
                #pragma unroll
                for (int k = 0; k < 8; ++k) w[k] = 0.f;
                s = 1.f;
            }
            float rr  = in ? 1.0f / s : 0.f;
            float acc = 0.f;
            #pragma unroll
            for (int k = 0; k < 8; ++k) { w[k] *= rr; acc += w[k]; }

            union { float4 f4; __half2 h[4]; } u;
            u.h[0] = __floats2half2_rn(w[0], w[1]);
            u.h[1] = __floats2half2_rn(w[2], w[3]);
            u.h[2] = __floats2half2_rn(w[4], w[5]);
            u.h[3] = __floats2half2_rn(w[6], w[7]);
            wv[i][0] = u.h[0]; wv[i][1] = u.h[1];
            wv[i][2] = u.h[2]; wv[i][3] = u.h[3];
            wcc[i] = in ? 1.0f - acc : 0.f;

            if (MODE == 0) {
                // store interior weights for launch 2 (each image px interior
                // to exactly one block)
                if ((unsigned)(gy - oy) < (unsigned)TILE &&
                    (unsigned)(gx - ox) < (unsigned)TILE) {
                    *(float4*)(wA + 4 * idx) = u.f4;
                    wC[idx] = wcc[i];
                }
            }
        }
    }
    __syncthreads();

    // ---- LDS byte addresses (low 32 bits of the flat LDS address = offset)
    const unsigned rA = (unsigned)(uintptr_t)&fA[(8 * g) * PITCH + c];
    const unsigned rB = (unsigned)(uintptr_t)&fB[(8 * g) * PITCH + c];
    const unsigned wAd = (unsigned)(uintptr_t)&fA[(8 * g + 1) * PITCH + sc];
    const unsigned wBd = (unsigned)(uintptr_t)&fB[(8 * g + 1) * PITCH + sc];

    // ---- 12 fused steps (6 periods x 2); paired DS ops, stride-1 b32 banks
    #pragma unroll 1
    for (int p = 0; p < 6; ++p) {
        {   // step s = 2p : fA -> fB
            const int s = 2 * p;
            const bool live = (8 * g + 8 >= s + 1) && (8 * g + 1 <= 64 - s);
            if (live) step_phase(rA, wBd, wv, wcc);
            __syncthreads();
        }
        {   // step s = 2p+1 : fB -> fA
            const int s = 2 * p + 1;
            const bool live = (8 * g + 8 >= s + 1) && (8 * g + 1 <= 64 - s);
            if (live) step_phase(rB, wAd, wv, wcc);
            __syncthreads();
        }
    }

    // ---- store 40x40 tile (result in fA after 12 steps)
    for (int i = tid; i < TILE * (TILE / 4); i += NT) {
        int r  = i / (TILE / 4);
        int c4 = (i - r * (TILE / 4)) * 4;
        const float* pp = fA + (IH + r) * PITCH + IH + c4;
        float4 v = make_float4(pp[0], pp[1], pp[2], pp[3]);
        *(float4*)&db[(size_t)(oy + r) * WIMG + ox + c4] = v;
    }
}

extern "C" void kernel_launch(void* const* d_in, const int* in_sizes, int n_in,
                              void* d_out, int out_size, void* d_ws, size_t ws_size,
                              hipStream_t stream)
{
    const float* aff  = (const float*)d_in[0];
    const float* feat = (const float*)d_in[1];
    float* out = (float*)d_out;

    char* ws = (char*)d_ws;
    float*   wsFrame = (float*)ws;
    __half2* wA      = (__half2*)(ws + WS_FRAME_B);
    float*   wC      = (float*)(ws + WS_FRAME_B + WS_WA_B);

    dim3 blk(NT, 1, 1);
    dim3 grd(WIMG / TILE, HIMG / TILE, BN);   // 16 x 12 x 8 = 1536 blocks

    if (ws_size >= WS_NEED) {
        affprop12<0><<<grd, blk, 0, stream>>>(aff, wA, wC, feat, wsFrame);
        affprop12<1><<<grd, blk, 0, stream>>>(aff, wA, wC, wsFrame, out);
    } else {
        affprop12<2><<<grd, blk, 0, stream>>>(aff, nullptr, nullptr, feat, wsFrame);
        affprop12<2><<<grd, blk, 0, stream>>>(aff, nullptr, nullptr, wsFrame, out);
    }
}